// Round 7
// baseline (109.438 us; speedup 1.0000x reference)
//
#include <hip/hip_runtime.h>
#include <math.h>

// Multitask loss, single kernel, ILP-2 (two independent rows in flight/thread):
//   loss = mean(bce(pb,tb)) + mean(bce(pt,tt)) + mean(CE(ps,ts))
//        + mean((pb>0)^(pt[:,0]>0)) + mean((pb>0)^(argmax(ps)>0))
// bce(x,y) = max(x,0) - x*y + log1p(exp(-|x|))
//
// Memory pattern = R2's (measured best: lane-stride-1 rows, ps as 4x float4,
// pt/tt as 5 scalar dwords). Changes vs R2:
//  - two-phase load->compute over ROW PAIRS so both rows' 17 loads issue
//    before either row's use; __launch_bounds__(256,4) caps VGPR at 128 so
//    the compiler doesn't serialize to save registers (R2/R4 sat at 24-36
//    VGPR with serialized chains).
//  - single kernel: per-block sums -> fixed-point (x2^32) integer atomicAdd
//    (order-independent => deterministic, validated in R5) + last-done block
//    writes out[0]. Saves the second launch+drain (~4-6us of 44.6).
// Fast intrinsics (__expf/__logf): tolerance 0.117 absmax on a ~5.8 scalar.

#define NBLOCKS 2048
#define NTHREADS 256
#define FIXED_SCALE 4294967296.0   // 2^32

__device__ __forceinline__ float bce_term(float x, float y) {
    // max(x,0) - x*y + log1p(exp(-|x|)); log arg in (1,2] -> no cancellation
    return fmaxf(x, 0.0f) - x * y + __logf(1.0f + __expf(-fabsf(x)));
}

struct Row {
    float4 s0, s1, s2, s3;      // ps[r, 0:16]
    float  ptv[5], ttv[5];      // pt[r,:], tt[r,:]
    float  xb, yb;              // pb[r], tb[r]
    int    tg;                  // ts[r]
};

__device__ __forceinline__ void load_row(Row& R,
    const float* __restrict__ pb, const float* __restrict__ pt,
    const float* __restrict__ ps, const float* __restrict__ tb,
    const float* __restrict__ tt, const int* __restrict__ ts, int r)
{
    const float4* ps4 = reinterpret_cast<const float4*>(ps + (size_t)r * 16);
    R.s0 = ps4[0]; R.s1 = ps4[1]; R.s2 = ps4[2]; R.s3 = ps4[3];
    const float* ptr = pt + (size_t)r * 5;
    const float* ttr = tt + (size_t)r * 5;
    #pragma unroll
    for (int j = 0; j < 5; ++j) { R.ptv[j] = ptr[j]; R.ttv[j] = ttr[j]; }
    R.xb = pb[r]; R.yb = tb[r]; R.tg = ts[r];
}

__device__ __forceinline__ float compute_row(const Row& R)
{
    float xs[16];  // static indexing only
    xs[0]  = R.s0.x; xs[1]  = R.s0.y; xs[2]  = R.s0.z; xs[3]  = R.s0.w;
    xs[4]  = R.s1.x; xs[5]  = R.s1.y; xs[6]  = R.s1.z; xs[7]  = R.s1.w;
    xs[8]  = R.s2.x; xs[9]  = R.s2.y; xs[10] = R.s2.z; xs[11] = R.s2.w;
    xs[12] = R.s3.x; xs[13] = R.s3.y; xs[14] = R.s3.z; xs[15] = R.s3.w;

    // argmax>0 <=> max(xs[1..15]) > xs[0] (strict, first-occurrence ties)
    float m15 = xs[1];
    #pragma unroll
    for (int j = 2; j < 16; ++j) m15 = fmaxf(m15, xs[j]);
    const float m = fmaxf(xs[0], m15);

    float se = 0.0f;
    float xt = 0.0f;  // xs[tg] via unrolled cndmask chain
    #pragma unroll
    for (int j = 0; j < 16; ++j) {
        se += __expf(xs[j] - m);
        xt = (j == R.tg) ? xs[j] : xt;
    }

    // task A
    float c = fmaxf(R.xb, 0.0f) - R.xb * R.yb +
              __logf(1.0f + __expf(-fabsf(R.xb)));
    // task C
    c += m + __logf(se) - xt;
    // task B (weight 1/5)
    float st = 0.0f;
    #pragma unroll
    for (int j = 0; j < 5; ++j) st += bce_term(R.ptv[j], R.ttv[j]);
    c += st * 0.2f;
    // XOR consistency terms
    const bool bc = R.xb > 0.0f;
    c += (bc != (R.ptv[0] > 0.0f)) ? 1.0f : 0.0f;
    c += (bc != (m15 > xs[0])) ? 1.0f : 0.0f;
    return c;
}

__global__ __launch_bounds__(NTHREADS, 4) void mtl_kernel(
    const float* __restrict__ pb,   // [B]    y_pred_binary
    const float* __restrict__ pt,   // [B,5]  y_pred_type
    const float* __restrict__ ps,   // [B,16] y_pred_source
    const float* __restrict__ tb,   // [B]    y_true_binary
    const float* __restrict__ tt,   // [B,5]  y_true_type
    const int*   __restrict__ ts,   // [B]    y_true_source
    unsigned long long* __restrict__ acc_fixed,  // ws, zeroed each call
    unsigned int* __restrict__ cnt,              // ws, zeroed each call
    float* __restrict__ out, int B)
{
    const int t  = threadIdx.x;
    const int r0 = blockIdx.x * NTHREADS + t;
    const int S  = NBLOCKS * NTHREADS;

    float acc = 0.0f;  // 4 rows (~30 max each): f32 exact enough (absmax 0 so far)

    if (B == 4 * S) {
        // fast path (B = 2^21): two row-pairs, loads of each pair independent
        #pragma unroll
        for (int k = 0; k < 2; ++k) {
            Row A, Bw;
            load_row(A,  pb, pt, ps, tb, tt, ts, r0 + (2 * k)     * S);
            load_row(Bw, pb, pt, ps, tb, tt, ts, r0 + (2 * k + 1) * S);
            acc += compute_row(A);
            acc += compute_row(Bw);
        }
    } else {
        for (int r = r0; r < B; r += S) {
            Row A;
            load_row(A, pb, pt, ps, tb, tt, ts, r);
            acc += compute_row(A);
        }
    }

    // ---- block reduction (wave shfl in f32, cross-wave via LDS) ----
    float a = acc;
    #pragma unroll
    for (int off = 32; off > 0; off >>= 1)
        a += __shfl_down(a, off, 64);

    __shared__ double smem[NTHREADS / 64];
    const int lane = t & 63;
    const int wave = t >> 6;
    if (lane == 0) smem[wave] = (double)a;
    __syncthreads();

    // ---- deterministic fixed-point global accumulate + last-block finish ----
    if (t == 0) {
        double s = 0.0;
        #pragma unroll
        for (int w = 0; w < NTHREADS / 64; ++w) s += smem[w];
        const unsigned long long v =
            (unsigned long long)(long long)llrint(s * FIXED_SCALE);
        atomicAdd(acc_fixed, v);            // integer add: order-independent
        __threadfence();
        const unsigned int done = atomicAdd(cnt, 1u);
        if (done == (unsigned int)(gridDim.x - 1)) {
            __threadfence();
            const unsigned long long tot = atomicAdd(acc_fixed, 0ull);
            out[0] = (float)((double)(long long)tot * (1.0 / FIXED_SCALE)
                             / (double)B);
        }
    }
}

extern "C" void kernel_launch(void* const* d_in, const int* in_sizes, int n_in,
                              void* d_out, int out_size, void* d_ws, size_t ws_size,
                              hipStream_t stream) {
    const float* pb = (const float*)d_in[0];
    const float* pt = (const float*)d_in[1];
    const float* ps = (const float*)d_in[2];
    const float* tb = (const float*)d_in[3];
    const float* tt = (const float*)d_in[4];
    const int*   ts = (const int*)d_in[5];
    float* out = (float*)d_out;
    const int B = in_sizes[0];

    unsigned long long* acc_fixed = (unsigned long long*)d_ws;
    unsigned int* cnt = (unsigned int*)((char*)d_ws + 8);

    hipMemsetAsync(d_ws, 0, 16, stream);  // zero acc + counter each call
    mtl_kernel<<<NBLOCKS, NTHREADS, 0, stream>>>(pb, pt, ps, tb, tt, ts,
                                                 acc_fixed, cnt, out, B);
}